// Round 1
// baseline (1408.038 us; speedup 1.0000x reference)
//
#include <hip/hip_runtime.h>
#include <math.h>

// ---- problem constants ----
static constexpr int N_   = 10000;
static constexpr int E_   = 160000;
static constexpr int G_   = 64;
static constexpr int T_   = 5;
static constexpr int FIN_ = 75;
static constexpr int ED_  = 50;
static constexpr int FOUT_= 15;
static constexpr int TF_  = T_*FIN_;     // 375
static constexpr int AGGW_= 4*FIN_;      // 300 per tower (mean,mn,mx,std)
static constexpr int TAGG_= T_*AGGW_;    // 1500
static constexpr int NIN_ = 2*TF_;       // 750 (A|B)
static constexpr int YC_  = 48;          // padded 45 -> 48 combined outputs

// ---- UAF ----
__device__ __forceinline__ float softplus_f(float x){
    return fmaxf(x, 0.f) + log1pf(expf(-fabsf(x)));
}
__device__ __forceinline__ float uaf_f(float v, const float* __restrict__ p){
    return softplus_f(p[0]*(v + p[1]) + p[2]*v*v) - softplus_f(p[3]*(v - p[1])) + p[4];
}

// ---- setup kernels ----
__global__ void k_h0(const int* __restrict__ x, const float* __restrict__ node_emb, float* __restrict__ h){
    int i = blockIdx.x*blockDim.x + threadIdx.x;
    if (i >= N_*FIN_) return;
    int n = i / FIN_, f = i % FIN_;
    h[i] = node_emb[x[n]*FIN_ + f];
}

__global__ void k_deg(const int* __restrict__ ei, int* __restrict__ deg_i){
    int e = blockIdx.x*blockDim.x + threadIdx.x;
    if (e >= E_) return;
    atomicAdd(&deg_i[ei[E_ + e]], 1);
}

__global__ void k_scan(const int* __restrict__ deg_i, int* __restrict__ offs, float* __restrict__ avglog){
    __shared__ int sd[1024];
    __shared__ float sf[1024];
    __shared__ int carry;
    if (threadIdx.x == 0) carry = 0;
    __syncthreads();
    float ls = 0.f;
    for (int base = 0; base < N_; base += 1024){
        int i = base + threadIdx.x;
        int v = (i < N_) ? deg_i[i] : 0;
        if (i < N_) ls += logf((float)v + 1.f);
        sd[threadIdx.x] = v;
        __syncthreads();
        for (int off = 1; off < 1024; off <<= 1){
            int t = (threadIdx.x >= off) ? sd[threadIdx.x - off] : 0;
            __syncthreads();
            sd[threadIdx.x] += t;
            __syncthreads();
        }
        if (i < N_) offs[i] = carry + sd[threadIdx.x] - v;
        __syncthreads();
        if (threadIdx.x == 0) carry += sd[1023];
        __syncthreads();
    }
    if (threadIdx.x == 0) offs[N_] = carry;
    sf[threadIdx.x] = ls;
    __syncthreads();
    for (int off = 512; off > 0; off >>= 1){
        if (threadIdx.x < off) sf[threadIdx.x] += sf[threadIdx.x + off];
        __syncthreads();
    }
    if (threadIdx.x == 0) avglog[0] = sf[0] / (float)N_;
}

__global__ void k_fill(const int* __restrict__ ei, const int* __restrict__ eattr,
                       const int* __restrict__ offs, int* __restrict__ cursor, int* __restrict__ csr){
    int e = blockIdx.x*blockDim.x + threadIdx.x;
    if (e >= E_) return;
    int d = ei[E_ + e];
    int pos = offs[d] + atomicAdd(&cursor[d], 1);
    csr[pos] = ei[e] | (eattr[e] << 16);
}

__global__ void k_amp(const int* __restrict__ deg_i, const float* __restrict__ avglog,
                      float* __restrict__ ampv, float* __restrict__ iampv){
    int n = blockIdx.x*blockDim.x + threadIdx.x;
    if (n >= N_) return;
    float dm = fmaxf((float)deg_i[n], 1.f);
    float a = logf(dm + 1.f) / avglog[0];
    ampv[n] = a;
    iampv[n] = 1.f / a;
}

// eemb[l,a,c] = sum_k edge_emb[a,k]*We[l,k,c] + be[l,c]
__global__ void k_eemb(const float* __restrict__ edge_emb, const float* __restrict__ We,
                       const float* __restrict__ be, float* __restrict__ eembw){
    int i = blockIdx.x*blockDim.x + threadIdx.x;
    if (i >= 4*4*FIN_) return;
    int c = i % FIN_;
    int a = (i / FIN_) % 4;
    int l = i / (4*FIN_);
    float s = be[l*FIN_ + c];
    for (int k = 0; k < ED_; k++) s = fmaf(edge_emb[a*ED_ + k], We[(l*ED_ + k)*FIN_ + c], s);
    eembw[i] = s;
}

// tbl[l,a,t,f] = sum_c eemb[l,a,c]*Wpre[l,t,150+c,f] + bpre[l,t,f]
__global__ void k_tbl(const float* __restrict__ eembw, const float* __restrict__ Wpre,
                      const float* __restrict__ bpre, float* __restrict__ tbl){
    int i = blockIdx.x*blockDim.x + threadIdx.x;
    if (i >= 4*4*TF_) return;
    int f = i % FIN_;
    int t = (i / FIN_) % T_;
    int a = (i / TF_) % 4;
    int l = i / (4*TF_);
    float s = bpre[(l*T_ + t)*FIN_ + f];
    const float* em = eembw + (l*4 + a)*FIN_;
    const float* W3 = Wpre + ((l*T_ + t)*225 + 2*FIN_)*FIN_;
    for (int c = 0; c < FIN_; c++) s = fmaf(em[c], W3[c*FIN_ + f], s);
    tbl[i] = s;
}

// Wcomb[l,t,c,j]: 375x48 per (l,t). cols 0..14=y1(fo), 15..29=y2, 30..44=y3, 45..47=0
__global__ void k_wcomb(const float* __restrict__ Wpost, float* __restrict__ Wcomb){
    int i = blockIdx.x*blockDim.x + threadIdx.x;
    if (i >= 4*T_*TF_*YC_) return;
    int j = i % YC_;
    int c = (i / YC_) % TF_;
    int t = (i / (YC_*TF_)) % T_;
    int l = i / (YC_*TF_*T_);
    float v = 0.f;
    if (j < 45){
        int blk = j / 15, fo = j % 15;
        const float* Wp = Wpost + (size_t)(l*T_ + t)*975*15;
        if (c < FIN_){ if (blk == 0) v = Wp[c*15 + fo]; }
        else { int jj = c - FIN_; v = Wp[(FIN_ + blk*AGGW_ + jj)*15 + fo]; }
    }
    Wcomb[i] = v;
}

// ---- per-layer kernels ----
// AB[n, 0:375] = A (h @ W1, per tower), AB[n, 375:750] = B (h @ W2)
static constexpr int KA_TM = 32;
__global__ void __launch_bounds__(256) k_A(const float* __restrict__ h, const float* __restrict__ Wpre_l,
                                           float* __restrict__ AB){
    __shared__ float hs[KA_TM][FIN_];
    int n0 = blockIdx.x * KA_TM;
    for (int idx = threadIdx.x; idx < KA_TM*FIN_; idx += 256){
        int m = idx / FIN_, c = idx % FIN_;
        int n = n0 + m;
        hs[m][c] = (n < N_) ? h[n*FIN_ + c] : 0.f;
    }
    __syncthreads();
    for (int j = threadIdx.x; j < NIN_; j += 256){
        int half = j / TF_;
        int tf = j % TF_;
        int t = tf / FIN_, f = tf % FIN_;
        const float* Wc = Wpre_l + ((t*225) + half*FIN_)*FIN_ + f;
        float acc[KA_TM];
        #pragma unroll
        for (int m = 0; m < KA_TM; m++) acc[m] = 0.f;
        for (int c = 0; c < FIN_; c++){
            float w = Wc[c*FIN_];
            #pragma unroll
            for (int m = 0; m < KA_TM; m++) acc[m] = fmaf(hs[m][c], w, acc[m]);
        }
        #pragma unroll
        for (int m = 0; m < KA_TM; m++){
            int n = n0 + m;
            if (n < N_) AB[(size_t)n*NIN_ + j] = acc[m];
        }
    }
}

// per-node CSR aggregation: agg[n,t, {mean,mn,mx,std} x 75]
__global__ void __launch_bounds__(128) k_agg(const float* __restrict__ AB, const int* __restrict__ offs,
                                             const int* __restrict__ csr, const float* __restrict__ tbl_l,
                                             float* __restrict__ agg){
    __shared__ float tl[4*TF_];
    int n = blockIdx.x;
    for (int idx = threadIdx.x; idx < 4*TF_; idx += 128) tl[idx] = tbl_l[idx];
    __syncthreads();
    int s = offs[n], e_end = offs[n+1];
    int f0 = threadIdx.x;
    int f1 = threadIdx.x + 128;
    int f2r = threadIdx.x + 256;
    int f2 = (f2r < TF_) ? f2r : 0;   // clamp; results for clamped lanes discarded
    const float* An = AB + (size_t)n*NIN_;
    float a0 = An[f0], a1 = An[f1], a2 = An[f2];
    float s0=0.f,s1=0.f,s2=0.f, q0=0.f,q1=0.f,q2=0.f;
    float mn0=INFINITY,mn1=INFINITY,mn2=INFINITY;
    float mx0=-INFINITY,mx1=-INFINITY,mx2=-INFINITY;
    for (int e = s; e < e_end; e++){
        int pk = csr[e];
        int src = pk & 0xFFFF;
        int at = pk >> 16;
        const float* B = AB + (size_t)src*NIN_ + TF_;
        const float* tt = tl + at*TF_;
        float m0 = a0 + B[f0] + tt[f0];
        float m1 = a1 + B[f1] + tt[f1];
        float m2 = a2 + B[f2] + tt[f2];
        s0 += m0; s1 += m1; s2 += m2;
        q0 = fmaf(m0,m0,q0); q1 = fmaf(m1,m1,q1); q2 = fmaf(m2,m2,q2);
        mn0 = fminf(mn0,m0); mn1 = fminf(mn1,m1); mn2 = fminf(mn2,m2);
        mx0 = fmaxf(mx0,m0); mx1 = fmaxf(mx1,m1); mx2 = fmaxf(mx2,m2);
    }
    float deg = (float)(e_end - s);
    float dc = fmaxf(deg, 1.f);
    float inv = 1.f / dc;
    bool empty = (deg == 0.f);
    float* aggn = agg + (size_t)n*TAGG_;
    {
        int f = f0;
        float mean = s0*inv, msq = q0*inv;
        float sd = sqrtf(fmaxf(msq - mean*mean, 0.f) + 1e-5f);
        float mnv = empty ? 0.f : mn0, mxv = empty ? 0.f : mx0;
        int t = f/FIN_, fi = f%FIN_;
        float* o = aggn + t*AGGW_ + fi;
        o[0] = mean; o[FIN_] = mnv; o[2*FIN_] = mxv; o[3*FIN_] = sd;
    }
    {
        int f = f1;
        float mean = s1*inv, msq = q1*inv;
        float sd = sqrtf(fmaxf(msq - mean*mean, 0.f) + 1e-5f);
        float mnv = empty ? 0.f : mn1, mxv = empty ? 0.f : mx1;
        int t = f/FIN_, fi = f%FIN_;
        float* o = aggn + t*AGGW_ + fi;
        o[0] = mean; o[FIN_] = mnv; o[2*FIN_] = mxv; o[3*FIN_] = sd;
    }
    if (f2r < TF_){
        int f = f2r;
        float mean = s2*inv, msq = q2*inv;
        float sd = sqrtf(fmaxf(msq - mean*mean, 0.f) + 1e-5f);
        float mnv = empty ? 0.f : mn2, mxv = empty ? 0.f : mx2;
        int t = f/FIN_, fi = f%FIN_;
        float* o = aggn + t*AGGW_ + fi;
        o[0] = mean; o[FIN_] = mnv; o[2*FIN_] = mxv; o[3*FIN_] = sd;
    }
}

// per-tower GEMM: Yb[n,t,0:48] = [h|agg_t] @ Wcomb[l,t]
static constexpr int PT_TM = 32;
__global__ void __launch_bounds__(192) k_post(const float* __restrict__ h, const float* __restrict__ agg,
                                              const float* __restrict__ Wcomb_l, float* __restrict__ Yb){
    __shared__ float In[PT_TM][TF_];
    int t = blockIdx.y;
    int n0 = blockIdx.x * PT_TM;
    for (int idx = threadIdx.x; idx < PT_TM*TF_; idx += 192){
        int m = idx / TF_, c = idx % TF_;
        int n = n0 + m;
        float v = 0.f;
        if (n < N_) v = (c < FIN_) ? h[n*FIN_ + c] : agg[(size_t)n*TAGG_ + t*AGGW_ + (c - FIN_)];
        In[m][c] = v;
    }
    __syncthreads();
    int j = threadIdx.x % YC_;
    int g = threadIdx.x / YC_;   // 0..3
    const float* W = Wcomb_l + t*TF_*YC_ + j;
    float acc[PT_TM/4];
    #pragma unroll
    for (int m = 0; m < PT_TM/4; m++) acc[m] = 0.f;
    for (int c = 0; c < TF_; c++){
        float w = W[c*YC_];
        #pragma unroll
        for (int m = 0; m < PT_TM/4; m++) acc[m] = fmaf(In[g + m*4][c], w, acc[m]);
    }
    #pragma unroll
    for (int m = 0; m < PT_TM/4; m++){
        int n = n0 + g + m*4;
        if (n < N_) Yb[((size_t)n*T_ + t)*YC_ + j] = acc[m];
    }
}

// combine + Wlin + BN stats
static constexpr int KY_TM = 16;
__global__ void __launch_bounds__(256) k_Y(const float* __restrict__ Yb, const float* __restrict__ ampv,
                                           const float* __restrict__ iampv, const float* __restrict__ bpost_l,
                                           const float* __restrict__ Wlin_l, const float* __restrict__ blin_l,
                                           float* __restrict__ olin, float* __restrict__ bnsum, float* __restrict__ bnsq){
    __shared__ float yl[KY_TM][FIN_];
    __shared__ float Wl[FIN_*FIN_];
    __shared__ float ov[KY_TM][FIN_];
    int n0 = blockIdx.x * KY_TM;
    for (int idx = threadIdx.x; idx < FIN_*FIN_; idx += 256) Wl[idx] = Wlin_l[idx];
    for (int idx = threadIdx.x; idx < KY_TM*FIN_; idx += 256){
        int m = idx / FIN_, p = idx % FIN_;
        int n = n0 + m;
        float v = 0.f;
        if (n < N_){
            int t = p / FOUT_, fo = p % FOUT_;
            const float* Yr = Yb + ((size_t)n*T_ + t)*YC_;
            v = Yr[fo] + ampv[n]*Yr[15 + fo] + iampv[n]*Yr[30 + fo] + bpost_l[t*FOUT_ + fo];
        }
        yl[m][p] = v;
    }
    __syncthreads();
    for (int idx = threadIdx.x; idx < KY_TM*FIN_; idx += 256){
        int m = idx / FIN_, q = idx % FIN_;
        float accv = blin_l[q];
        for (int p = 0; p < FIN_; p++) accv = fmaf(yl[m][p], Wl[p*FIN_ + q], accv);
        ov[m][q] = accv;
        int n = n0 + m;
        if (n < N_) olin[(size_t)n*FIN_ + q] = accv;
    }
    __syncthreads();
    if (threadIdx.x < FIN_){
        int q = threadIdx.x;
        float s = 0.f, s2 = 0.f;
        int mmax = min(KY_TM, N_ - n0);
        for (int m = 0; m < mmax; m++){ float v = ov[m][q]; s += v; s2 = fmaf(v, v, s2); }
        atomicAdd(&bnsum[q], s);
        atomicAdd(&bnsq[q], s2);
    }
}

__global__ void k_bn(const float* __restrict__ olin, const float* __restrict__ bnsum, const float* __restrict__ bnsq,
                     const float* __restrict__ gamma_l, const float* __restrict__ beta_l,
                     const float* __restrict__ uafp, float* __restrict__ h){
    int i = blockIdx.x*blockDim.x + threadIdx.x;
    if (i >= N_*FIN_) return;
    int q = i % FIN_;
    float mu = bnsum[q] * (1.f/(float)N_);
    float var = bnsq[q] * (1.f/(float)N_) - mu*mu;
    float xh = (olin[i] - mu) * rsqrtf(var + 1e-5f) * gamma_l[q] + beta_l[q];
    h[i] = uaf_f(xh, uafp);
}

// ---- pooling + MLP ----
__global__ void k_pool(const float* __restrict__ h, const int* __restrict__ batch, float* __restrict__ pooled){
    int i = blockIdx.x*blockDim.x + threadIdx.x;
    if (i >= N_*FIN_) return;
    int n = i / FIN_, q = i % FIN_;
    atomicAdd(&pooled[batch[n]*FIN_ + q], h[i]);
}

__global__ void __launch_bounds__(64) k_mlp(const float* __restrict__ pooled,
        const float* __restrict__ mW1, const float* __restrict__ mb1,
        const float* __restrict__ mW2, const float* __restrict__ mb2,
        const float* __restrict__ mW3, const float* __restrict__ mb3,
        const float* __restrict__ uafp, float* __restrict__ outp){
    __shared__ float pr[FIN_];
    __shared__ float z1[50];
    __shared__ float z2[25];
    int g = blockIdx.x;
    for (int c = threadIdx.x; c < FIN_; c += 64) pr[c] = pooled[g*FIN_ + c];
    __syncthreads();
    if (threadIdx.x < 50){
        float s = mb1[threadIdx.x];
        for (int c = 0; c < FIN_; c++) s = fmaf(pr[c], mW1[c*50 + threadIdx.x], s);
        z1[threadIdx.x] = uaf_f(s, uafp);
    }
    __syncthreads();
    if (threadIdx.x < 25){
        float s = mb2[threadIdx.x];
        for (int c = 0; c < 50; c++) s = fmaf(z1[c], mW2[c*25 + threadIdx.x], s);
        z2[threadIdx.x] = uaf_f(s, uafp);
    }
    __syncthreads();
    if (threadIdx.x == 0){
        float s = mb3[0];
        for (int c = 0; c < 25; c++) s = fmaf(z2[c], mW3[c], s);
        outp[g] = s;
    }
}

extern "C" void kernel_launch(void* const* d_in, const int* in_sizes, int n_in,
                              void* d_out, int out_size, void* d_ws, size_t ws_size,
                              hipStream_t stream) {
    const int* x         = (const int*)d_in[0];
    const int* ei        = (const int*)d_in[1];
    const int* eattr     = (const int*)d_in[2];
    const int* batch     = (const int*)d_in[3];
    const float* node_emb= (const float*)d_in[4];
    const float* edge_emb= (const float*)d_in[5];
    const float* We      = (const float*)d_in[6];
    const float* be      = (const float*)d_in[7];
    const float* Wpre    = (const float*)d_in[8];
    const float* bpre    = (const float*)d_in[9];
    const float* Wpost   = (const float*)d_in[10];
    const float* bpost   = (const float*)d_in[11];
    const float* Wlin    = (const float*)d_in[12];
    const float* blin    = (const float*)d_in[13];
    const float* bn_gamma= (const float*)d_in[14];
    const float* bn_beta = (const float*)d_in[15];
    const float* uafp    = (const float*)d_in[16];
    const float* mW1     = (const float*)d_in[17];
    const float* mb1     = (const float*)d_in[18];
    const float* mW2     = (const float*)d_in[19];
    const float* mb2     = (const float*)d_in[20];
    const float* mW3     = (const float*)d_in[21];
    const float* mb3     = (const float*)d_in[22];
    float* outp          = (float*)d_out;

    char* w = (char*)d_ws;
    auto alloc = [&](size_t bytes) -> void* {
        void* p = (void*)w;
        w += (bytes + 255) & ~(size_t)255;
        return p;
    };
    float* h     = (float*)alloc((size_t)N_*FIN_*4);
    float* olin  = (float*)alloc((size_t)N_*FIN_*4);
    float* AB    = (float*)alloc((size_t)N_*NIN_*4);
    float* aggb  = (float*)alloc((size_t)N_*TAGG_*4);
    float* Yb    = AB;  // alias: AB dead after k_agg, Yb born in k_post
    float* ampv  = (float*)alloc(N_*4);
    float* iampv = (float*)alloc(N_*4);
    float* avglog= (float*)alloc(4);
    float* tbl   = (float*)alloc(4*4*TF_*4);
    float* eembw = (float*)alloc(4*4*FIN_*4);
    float* Wcomb = (float*)alloc((size_t)4*T_*TF_*YC_*4);
    float* bnsum = (float*)alloc(2*FIN_*4);
    float* bnsq  = bnsum + FIN_;
    float* pooled= (float*)alloc(G_*FIN_*4);
    int* deg_i   = (int*)alloc(N_*4);
    int* offs    = (int*)alloc((N_+1)*4);
    int* cursor  = (int*)alloc(N_*4);
    int* csr     = (int*)alloc(E_*4);

    hipMemsetAsync(deg_i, 0, N_*4, stream);
    hipMemsetAsync(cursor, 0, N_*4, stream);
    hipMemsetAsync(pooled, 0, G_*FIN_*4, stream);

    k_h0<<<(N_*FIN_ + 255)/256, 256, 0, stream>>>(x, node_emb, h);
    k_deg<<<(E_ + 255)/256, 256, 0, stream>>>(ei, deg_i);
    k_scan<<<1, 1024, 0, stream>>>(deg_i, offs, avglog);
    k_fill<<<(E_ + 255)/256, 256, 0, stream>>>(ei, eattr, offs, cursor, csr);
    k_amp<<<(N_ + 255)/256, 256, 0, stream>>>(deg_i, avglog, ampv, iampv);
    k_eemb<<<(4*4*FIN_ + 255)/256, 256, 0, stream>>>(edge_emb, We, be, eembw);
    k_tbl<<<(4*4*TF_ + 255)/256, 256, 0, stream>>>(eembw, Wpre, bpre, tbl);
    k_wcomb<<<(4*T_*TF_*YC_ + 255)/256, 256, 0, stream>>>(Wpost, Wcomb);

    for (int l = 0; l < 4; l++){
        hipMemsetAsync(bnsum, 0, 2*FIN_*4, stream);
        k_A<<<(N_ + KA_TM - 1)/KA_TM, 256, 0, stream>>>(h, Wpre + (size_t)l*T_*225*FIN_, AB);
        k_agg<<<N_, 128, 0, stream>>>(AB, offs, csr, tbl + (size_t)l*4*TF_, aggb);
        dim3 gp((N_ + PT_TM - 1)/PT_TM, T_);
        k_post<<<gp, 192, 0, stream>>>(h, aggb, Wcomb + (size_t)l*T_*TF_*YC_, Yb);
        k_Y<<<(N_ + KY_TM - 1)/KY_TM, 256, 0, stream>>>(Yb, ampv, iampv, bpost + l*T_*FOUT_,
                                                        Wlin + (size_t)l*FIN_*FIN_, blin + l*FIN_,
                                                        olin, bnsum, bnsq);
        k_bn<<<(N_*FIN_ + 255)/256, 256, 0, stream>>>(olin, bnsum, bnsq,
                                                      bn_gamma + l*FIN_, bn_beta + l*FIN_, uafp, h);
    }

    k_pool<<<(N_*FIN_ + 255)/256, 256, 0, stream>>>(h, batch, pooled);
    k_mlp<<<G_, 64, 0, stream>>>(pooled, mW1, mb1, mW2, mb2, mW3, mb3, uafp, outp);
}

// Round 2
// 1050.715 us; speedup vs baseline: 1.3401x; 1.3401x over previous
//
#include <hip/hip_runtime.h>
#include <math.h>

// ---- problem constants ----
static constexpr int N_   = 10000;
static constexpr int E_   = 160000;
static constexpr int G_   = 64;
static constexpr int T_   = 5;
static constexpr int FIN_ = 75;
static constexpr int ED_  = 50;
static constexpr int FOUT_= 15;
static constexpr int TF_  = T_*FIN_;     // 375
static constexpr int AGGW_= 4*FIN_;      // 300 per tower (mean,mn,mx,std)
static constexpr int TAGG_= T_*AGGW_;    // 1500
static constexpr int YC_  = 48;          // padded 45 -> 48 combined outputs
static constexpr int H80  = 80;          // padded h row (16B-aligned float4 rows)
static constexpr int ABW_ = 800;         // AB row: 10 chunks x 80

// ---- UAF ----
__device__ __forceinline__ float softplus_f(float x){
    return fmaxf(x, 0.f) + log1pf(expf(-fabsf(x)));
}
__device__ __forceinline__ float uaf_f(float v, const float* __restrict__ p){
    return softplus_f(p[0]*(v + p[1]) + p[2]*v*v) - softplus_f(p[3]*(v - p[1])) + p[4];
}

// ---- setup kernels ----
__global__ void k_h0(const int* __restrict__ x, const float* __restrict__ node_emb, float* __restrict__ h80){
    int i = blockIdx.x*blockDim.x + threadIdx.x;
    if (i >= N_*H80) return;
    int n = i / H80, f = i % H80;
    h80[i] = (f < FIN_) ? node_emb[x[n]*FIN_ + f] : 0.f;
}

__global__ void k_deg(const int* __restrict__ ei, int* __restrict__ deg_i){
    int e = blockIdx.x*blockDim.x + threadIdx.x;
    if (e >= E_) return;
    atomicAdd(&deg_i[ei[E_ + e]], 1);
}

__global__ void k_scan(const int* __restrict__ deg_i, int* __restrict__ offs, float* __restrict__ avglog){
    __shared__ int sd[1024];
    __shared__ float sf[1024];
    __shared__ int carry;
    if (threadIdx.x == 0) carry = 0;
    __syncthreads();
    float ls = 0.f;
    for (int base = 0; base < N_; base += 1024){
        int i = base + threadIdx.x;
        int v = (i < N_) ? deg_i[i] : 0;
        if (i < N_) ls += logf((float)v + 1.f);
        sd[threadIdx.x] = v;
        __syncthreads();
        for (int off = 1; off < 1024; off <<= 1){
            int t = (threadIdx.x >= off) ? sd[threadIdx.x - off] : 0;
            __syncthreads();
            sd[threadIdx.x] += t;
            __syncthreads();
        }
        if (i < N_) offs[i] = carry + sd[threadIdx.x] - v;
        __syncthreads();
        if (threadIdx.x == 0) carry += sd[1023];
        __syncthreads();
    }
    if (threadIdx.x == 0) offs[N_] = carry;
    sf[threadIdx.x] = ls;
    __syncthreads();
    for (int off = 512; off > 0; off >>= 1){
        if (threadIdx.x < off) sf[threadIdx.x] += sf[threadIdx.x + off];
        __syncthreads();
    }
    if (threadIdx.x == 0) avglog[0] = sf[0] / (float)N_;
}

__global__ void k_fill(const int* __restrict__ ei, const int* __restrict__ eattr,
                       const int* __restrict__ offs, int* __restrict__ cursor, int* __restrict__ csr){
    int e = blockIdx.x*blockDim.x + threadIdx.x;
    if (e >= E_) return;
    int d = ei[E_ + e];
    int pos = offs[d] + atomicAdd(&cursor[d], 1);
    csr[pos] = ei[e] | (eattr[e] << 16);
}

__global__ void k_amp(const int* __restrict__ deg_i, const float* __restrict__ avglog,
                      float* __restrict__ ampv, float* __restrict__ iampv){
    int n = blockIdx.x*blockDim.x + threadIdx.x;
    if (n >= N_) return;
    float dm = fmaxf((float)deg_i[n], 1.f);
    float a = logf(dm + 1.f) / avglog[0];
    ampv[n] = a;
    iampv[n] = 1.f / a;
}

__global__ void k_eemb(const float* __restrict__ edge_emb, const float* __restrict__ We,
                       const float* __restrict__ be, float* __restrict__ eembw){
    int i = blockIdx.x*blockDim.x + threadIdx.x;
    if (i >= 4*4*FIN_) return;
    int c = i % FIN_;
    int a = (i / FIN_) % 4;
    int l = i / (4*FIN_);
    float s = be[l*FIN_ + c];
    for (int k = 0; k < ED_; k++) s = fmaf(edge_emb[a*ED_ + k], We[(l*ED_ + k)*FIN_ + c], s);
    eembw[i] = s;
}

__global__ void k_tbl(const float* __restrict__ eembw, const float* __restrict__ Wpre,
                      const float* __restrict__ bpre, float* __restrict__ tbl){
    int i = blockIdx.x*blockDim.x + threadIdx.x;
    if (i >= 4*4*TF_) return;
    int f = i % FIN_;
    int t = (i / FIN_) % T_;
    int a = (i / TF_) % 4;
    int l = i / (4*TF_);
    float s = bpre[(l*T_ + t)*FIN_ + f];
    const float* em = eembw + (l*4 + a)*FIN_;
    const float* W3 = Wpre + ((size_t)(l*T_ + t)*225 + 2*FIN_)*FIN_;
    for (int c = 0; c < FIN_; c++) s = fmaf(em[c], W3[c*FIN_ + f], s);
    tbl[i] = s;
}

// Wcomb[l,t,c,j]: 375x48 per (l,t). cols 0..14=y1, 15..29=y2(amp), 30..44=y3(iamp), 45..47=0
__global__ void k_wcomb(const float* __restrict__ Wpost, float* __restrict__ Wcomb){
    int i = blockIdx.x*blockDim.x + threadIdx.x;
    if (i >= 4*T_*TF_*YC_) return;
    int j = i % YC_;
    int c = (i / YC_) % TF_;
    int t = (i / (YC_*TF_)) % T_;
    int l = i / (YC_*TF_*T_);
    float v = 0.f;
    if (j < 45){
        int blk = j / 15, fo = j % 15;
        const float* Wp = Wpost + (size_t)(l*T_ + t)*975*15;
        if (c < FIN_){ if (blk == 0) v = Wp[c*15 + fo]; }
        else { int jj = c - FIN_; v = Wp[(FIN_ + blk*AGGW_ + jj)*15 + fo]; }
    }
    Wcomb[i] = v;
}

// ---- per-layer kernels ----
// thread-per-row GEMM: AB[n, chunk*80 + 0..74] = h_row @ W_block(75x75), chunk = t*2+half
__global__ void __launch_bounds__(128) k_A(const float* __restrict__ h80, const float* __restrict__ Wpre_l,
                                           float* __restrict__ AB){
    __shared__ float Wl[76*H80];
    int chunk = blockIdx.y;
    int t = chunk >> 1, half = chunk & 1;
    const float* Wsrc = Wpre_l + (size_t)(t*225 + half*FIN_)*FIN_;
    for (int idx = threadIdx.x; idx < 76*H80; idx += 128) Wl[idx] = 0.f;
    __syncthreads();
    for (int idx = threadIdx.x; idx < FIN_*FIN_; idx += 128)
        Wl[(idx/FIN_)*H80 + (idx%FIN_)] = Wsrc[idx];
    __syncthreads();
    int n = blockIdx.x*128 + threadIdx.x;
    int nn = (n < N_) ? n : N_-1;
    const float4* hrow = (const float4*)(h80 + (size_t)nn*H80);
    float4 a4[19];
    #pragma unroll
    for (int j = 0; j < 19; j++) a4[j] = make_float4(0.f,0.f,0.f,0.f);
    #pragma unroll 1
    for (int c4 = 0; c4 < 19; c4++){
        float4 hv = hrow[c4];
        #pragma unroll
        for (int k = 0; k < 4; k++){
            float hc = (&hv.x)[k];
            const float4* wr = (const float4*)(Wl + (c4*4 + k)*H80);
            #pragma unroll
            for (int j = 0; j < 19; j++){
                float4 wv = wr[j];
                a4[j].x = fmaf(hc, wv.x, a4[j].x);
                a4[j].y = fmaf(hc, wv.y, a4[j].y);
                a4[j].z = fmaf(hc, wv.z, a4[j].z);
                a4[j].w = fmaf(hc, wv.w, a4[j].w);
            }
        }
    }
    if (n < N_){
        float4* ob = (float4*)(AB + (size_t)n*ABW_ + chunk*H80);
        #pragma unroll
        for (int j = 0; j < 19; j++) ob[j] = a4[j];
    }
}

// per-node CSR aggregation: agg[n,t, {mean,mn,mx,std} x 75]
__global__ void __launch_bounds__(128) k_agg(const float* __restrict__ AB, const int* __restrict__ offs,
                                             const int* __restrict__ csr, const float* __restrict__ tbl_l,
                                             float* __restrict__ agg){
    __shared__ float tl[4*TF_];
    int n = blockIdx.x;
    for (int idx = threadIdx.x; idx < 4*TF_; idx += 128) tl[idx] = tbl_l[idx];
    __syncthreads();
    int s = offs[n], e_end = offs[n+1];
    int f0 = threadIdx.x;
    int f1 = threadIdx.x + 128;
    int f2r = threadIdx.x + 256;
    int f2 = (f2r < TF_) ? f2r : 0;
    int ao0 = (f0/FIN_)*160 + f0%FIN_;
    int ao1 = (f1/FIN_)*160 + f1%FIN_;
    int ao2 = (f2/FIN_)*160 + f2%FIN_;
    const float* An = AB + (size_t)n*ABW_;
    float a0 = An[ao0], a1 = An[ao1], a2 = An[ao2];
    float s0=0.f,s1=0.f,s2=0.f, q0=0.f,q1=0.f,q2=0.f;
    float mn0=INFINITY,mn1=INFINITY,mn2=INFINITY;
    float mx0=-INFINITY,mx1=-INFINITY,mx2=-INFINITY;
    for (int e = s; e < e_end; e++){
        int pk = csr[e];
        int src = pk & 0xFFFF;
        int at = pk >> 16;
        const float* B = AB + (size_t)src*ABW_ + 80;
        const float* tt = tl + at*TF_;
        float m0 = a0 + B[ao0] + tt[f0];
        float m1 = a1 + B[ao1] + tt[f1];
        float m2 = a2 + B[ao2] + tt[f2];
        s0 += m0; s1 += m1; s2 += m2;
        q0 = fmaf(m0,m0,q0); q1 = fmaf(m1,m1,q1); q2 = fmaf(m2,m2,q2);
        mn0 = fminf(mn0,m0); mn1 = fminf(mn1,m1); mn2 = fminf(mn2,m2);
        mx0 = fmaxf(mx0,m0); mx1 = fmaxf(mx1,m1); mx2 = fmaxf(mx2,m2);
    }
    float deg = (float)(e_end - s);
    float dc = fmaxf(deg, 1.f);
    float inv = 1.f / dc;
    bool empty = (deg == 0.f);
    float* aggn = agg + (size_t)n*TAGG_;
    {
        float mean = s0*inv, msq = q0*inv;
        float sd = sqrtf(fmaxf(msq - mean*mean, 0.f) + 1e-5f);
        int t = f0/FIN_, fi = f0%FIN_;
        float* o = aggn + t*AGGW_ + fi;
        o[0] = mean; o[FIN_] = empty?0.f:mn0; o[2*FIN_] = empty?0.f:mx0; o[3*FIN_] = sd;
    }
    {
        float mean = s1*inv, msq = q1*inv;
        float sd = sqrtf(fmaxf(msq - mean*mean, 0.f) + 1e-5f);
        int t = f1/FIN_, fi = f1%FIN_;
        float* o = aggn + t*AGGW_ + fi;
        o[0] = mean; o[FIN_] = empty?0.f:mn1; o[2*FIN_] = empty?0.f:mx1; o[3*FIN_] = sd;
    }
    if (f2r < TF_){
        float mean = s2*inv, msq = q2*inv;
        float sd = sqrtf(fmaxf(msq - mean*mean, 0.f) + 1e-5f);
        int t = f2r/FIN_, fi = f2r%FIN_;
        float* o = aggn + t*AGGW_ + fi;
        o[0] = mean; o[FIN_] = empty?0.f:mn2; o[2*FIN_] = empty?0.f:mx2; o[3*FIN_] = sd;
    }
}

// thread-per-row: Yb[n,t,0:48] = [h(75) | agg_t(300)] @ Wcomb[l,t]  (K=375)
__global__ void __launch_bounds__(128) k_post2(const float* __restrict__ h80, const float* __restrict__ aggb,
                                               const float* __restrict__ Wcomb_l, float* __restrict__ Yb){
    __shared__ float Wc[100*YC_];   // 19.2 KB
    int t = blockIdx.y;
    int n = blockIdx.x*128 + threadIdx.x;
    int nn = (n < N_) ? n : N_-1;
    const float* Wbase = Wcomb_l + (size_t)t*TF_*YC_;
    float4 a4[12];
    #pragma unroll
    for (int j = 0; j < 12; j++) a4[j] = make_float4(0.f,0.f,0.f,0.f);
    // seg0: h-part, W rows 0..75 (row 75 pairs with h pad=0 -> contributes 0)
    for (int idx = threadIdx.x; idx < 76*YC_; idx += 128) Wc[idx] = Wbase[idx];
    __syncthreads();
    const float4* hrow = (const float4*)(h80 + (size_t)nn*H80);
    #pragma unroll 2
    for (int c4 = 0; c4 < 19; c4++){
        float4 hv = hrow[c4];
        #pragma unroll
        for (int k = 0; k < 4; k++){
            float hc = (&hv.x)[k];
            const float4* wr = (const float4*)(Wc + (c4*4 + k)*YC_);
            #pragma unroll
            for (int j = 0; j < 12; j++){
                float4 wv = wr[j];
                a4[j].x = fmaf(hc, wv.x, a4[j].x);
                a4[j].y = fmaf(hc, wv.y, a4[j].y);
                a4[j].z = fmaf(hc, wv.z, a4[j].z);
                a4[j].w = fmaf(hc, wv.w, a4[j].w);
            }
        }
    }
    // agg segs: 3 chunks of 100 K-rows
    const float4* arow = (const float4*)(aggb + (size_t)nn*TAGG_ + t*AGGW_);
    for (int seg = 0; seg < 3; seg++){
        __syncthreads();
        const float* Ws = Wbase + (FIN_ + seg*100)*YC_;
        for (int idx = threadIdx.x; idx < 100*YC_; idx += 128) Wc[idx] = Ws[idx];
        __syncthreads();
        #pragma unroll 2
        for (int c4 = 0; c4 < 25; c4++){
            float4 av = arow[seg*25 + c4];
            #pragma unroll
            for (int k = 0; k < 4; k++){
                float ac = (&av.x)[k];
                const float4* wr = (const float4*)(Wc + (c4*4 + k)*YC_);
                #pragma unroll
                for (int j = 0; j < 12; j++){
                    float4 wv = wr[j];
                    a4[j].x = fmaf(ac, wv.x, a4[j].x);
                    a4[j].y = fmaf(ac, wv.y, a4[j].y);
                    a4[j].z = fmaf(ac, wv.z, a4[j].z);
                    a4[j].w = fmaf(ac, wv.w, a4[j].w);
                }
            }
        }
    }
    if (n < N_){
        float4* yb4 = (float4*)(Yb + ((size_t)n*T_ + t)*YC_);
        #pragma unroll
        for (int j = 0; j < 12; j++) yb4[j] = a4[j];
    }
}

// combine + Wlin + BN stats: 32-row tile, 256 threads (m=tid&31, g=tid>>5 -> cols g+8k)
__global__ void __launch_bounds__(256) k_Y(const float* __restrict__ Yb, const float* __restrict__ ampv,
                                           const float* __restrict__ iampv, const float* __restrict__ bpost_l,
                                           const float* __restrict__ Wlin_l, const float* __restrict__ blin_l,
                                           float* __restrict__ olin, float* __restrict__ bnsum, float* __restrict__ bnsq){
    __shared__ float yt[32*77];
    __shared__ float Wl[FIN_*80];   // padded cols 75..79 = 0
    int n0 = blockIdx.x * 32;
    for (int idx = threadIdx.x; idx < FIN_*80; idx += 256) Wl[idx] = 0.f;
    __syncthreads();
    for (int idx = threadIdx.x; idx < FIN_*FIN_; idx += 256)
        Wl[(idx/FIN_)*80 + (idx%FIN_)] = Wlin_l[idx];
    for (int idx = threadIdx.x; idx < 32*FIN_; idx += 256){
        int m = idx / FIN_, p = idx % FIN_;
        int n = n0 + m;
        float v = 0.f;
        if (n < N_){
            int t = p / FOUT_, fo = p % FOUT_;
            const float* Yr = Yb + ((size_t)n*T_ + t)*YC_;
            v = Yr[fo] + ampv[n]*Yr[15 + fo] + iampv[n]*Yr[30 + fo] + bpost_l[t*FOUT_ + fo];
        }
        yt[m*77 + p] = v;
    }
    __syncthreads();
    int m = threadIdx.x & 31, g = threadIdx.x >> 5;   // g in 0..7
    float acc[10];
    #pragma unroll
    for (int k = 0; k < 10; k++) acc[k] = 0.f;
    for (int p = 0; p < FIN_; p++){
        float yv = yt[m*77 + p];
        const float* wp = Wl + p*80 + g;
        #pragma unroll
        for (int k = 0; k < 10; k++) acc[k] = fmaf(yv, wp[k*8], acc[k]);
    }
    int n = n0 + m;
    bool valid = (n < N_);
    __syncthreads();   // done reading yt; reuse as ov
    #pragma unroll
    for (int k = 0; k < 10; k++){
        int j = g + k*8;
        if (j < FIN_){
            float v = valid ? (acc[k] + blin_l[j]) : 0.f;
            yt[m*77 + j] = v;
            if (valid) olin[(size_t)n*FIN_ + j] = v;
        }
    }
    __syncthreads();
    if (threadIdx.x < FIN_){
        int q = threadIdx.x;
        float s = 0.f, s2 = 0.f;
        for (int mm = 0; mm < 32; mm++){ float v = yt[mm*77 + q]; s += v; s2 = fmaf(v, v, s2); }
        atomicAdd(&bnsum[q], s);
        atomicAdd(&bnsq[q], s2);
    }
}

__global__ void k_bn(const float* __restrict__ olin, const float* __restrict__ bnsum, const float* __restrict__ bnsq,
                     const float* __restrict__ gamma_l, const float* __restrict__ beta_l,
                     const float* __restrict__ uafp, float* __restrict__ h80){
    int i = blockIdx.x*blockDim.x + threadIdx.x;
    if (i >= N_*H80) return;
    int n = i / H80, q = i % H80;
    if (q >= FIN_){ h80[i] = 0.f; return; }
    float mu = bnsum[q] * (1.f/(float)N_);
    float var = bnsq[q] * (1.f/(float)N_) - mu*mu;
    float xh = (olin[(size_t)n*FIN_ + q] - mu) * rsqrtf(var + 1e-5f) * gamma_l[q] + beta_l[q];
    h80[i] = uaf_f(xh, uafp);
}

// ---- pooling + MLP ----
__global__ void k_pool(const float* __restrict__ h80, const int* __restrict__ batch, float* __restrict__ pooled){
    int i = blockIdx.x*blockDim.x + threadIdx.x;
    if (i >= N_*FIN_) return;
    int n = i / FIN_, q = i % FIN_;
    atomicAdd(&pooled[batch[n]*FIN_ + q], h80[(size_t)n*H80 + q]);
}

__global__ void __launch_bounds__(64) k_mlp(const float* __restrict__ pooled,
        const float* __restrict__ mW1, const float* __restrict__ mb1,
        const float* __restrict__ mW2, const float* __restrict__ mb2,
        const float* __restrict__ mW3, const float* __restrict__ mb3,
        const float* __restrict__ uafp, float* __restrict__ outp){
    __shared__ float pr[FIN_];
    __shared__ float z1[50];
    __shared__ float z2[25];
    int g = blockIdx.x;
    for (int c = threadIdx.x; c < FIN_; c += 64) pr[c] = pooled[g*FIN_ + c];
    __syncthreads();
    if (threadIdx.x < 50){
        float s = mb1[threadIdx.x];
        for (int c = 0; c < FIN_; c++) s = fmaf(pr[c], mW1[c*50 + threadIdx.x], s);
        z1[threadIdx.x] = uaf_f(s, uafp);
    }
    __syncthreads();
    if (threadIdx.x < 25){
        float s = mb2[threadIdx.x];
        for (int c = 0; c < 50; c++) s = fmaf(z1[c], mW2[c*25 + threadIdx.x], s);
        z2[threadIdx.x] = uaf_f(s, uafp);
    }
    __syncthreads();
    if (threadIdx.x == 0){
        float s = mb3[0];
        for (int c = 0; c < 25; c++) s = fmaf(z2[c], mW3[c], s);
        outp[g] = s;
    }
}

extern "C" void kernel_launch(void* const* d_in, const int* in_sizes, int n_in,
                              void* d_out, int out_size, void* d_ws, size_t ws_size,
                              hipStream_t stream) {
    const int* x         = (const int*)d_in[0];
    const int* ei        = (const int*)d_in[1];
    const int* eattr     = (const int*)d_in[2];
    const int* batch     = (const int*)d_in[3];
    const float* node_emb= (const float*)d_in[4];
    const float* edge_emb= (const float*)d_in[5];
    const float* We      = (const float*)d_in[6];
    const float* be      = (const float*)d_in[7];
    const float* Wpre    = (const float*)d_in[8];
    const float* bpre    = (const float*)d_in[9];
    const float* Wpost   = (const float*)d_in[10];
    const float* bpost   = (const float*)d_in[11];
    const float* Wlin    = (const float*)d_in[12];
    const float* blin    = (const float*)d_in[13];
    const float* bn_gamma= (const float*)d_in[14];
    const float* bn_beta = (const float*)d_in[15];
    const float* uafp    = (const float*)d_in[16];
    const float* mW1     = (const float*)d_in[17];
    const float* mb1     = (const float*)d_in[18];
    const float* mW2     = (const float*)d_in[19];
    const float* mb2     = (const float*)d_in[20];
    const float* mW3     = (const float*)d_in[21];
    const float* mb3     = (const float*)d_in[22];
    float* outp          = (float*)d_out;

    char* w = (char*)d_ws;
    auto alloc = [&](size_t bytes) -> void* {
        void* p = (void*)w;
        w += (bytes + 255) & ~(size_t)255;
        return p;
    };
    float* h80   = (float*)alloc((size_t)N_*H80*4);
    float* AB    = (float*)alloc((size_t)N_*ABW_*4);   // 32 MB
    float* aggb  = (float*)alloc((size_t)N_*TAGG_*4);  // 60 MB
    float* Yb    = AB;                  // alias: AB dead after k_agg
    float* olin  = AB + 4000000;        // alias: 16MB offset, disjoint from Yb (9.6MB)
    float* ampv  = (float*)alloc(N_*4);
    float* iampv = (float*)alloc(N_*4);
    float* avglog= (float*)alloc(4);
    float* tbl   = (float*)alloc(4*4*TF_*4);
    float* eembw = (float*)alloc(4*4*FIN_*4);
    float* Wcomb = (float*)alloc((size_t)4*T_*TF_*YC_*4);
    float* bnsum = (float*)alloc(2*FIN_*4);
    float* bnsq  = bnsum + FIN_;
    float* pooled= (float*)alloc(G_*FIN_*4);
    int* deg_i   = (int*)alloc(N_*4);
    int* offs    = (int*)alloc((N_+1)*4);
    int* cursor  = (int*)alloc(N_*4);
    int* csr     = (int*)alloc(E_*4);

    hipMemsetAsync(deg_i, 0, N_*4, stream);
    hipMemsetAsync(cursor, 0, N_*4, stream);
    hipMemsetAsync(pooled, 0, G_*FIN_*4, stream);

    k_h0<<<(N_*H80 + 255)/256, 256, 0, stream>>>(x, node_emb, h80);
    k_deg<<<(E_ + 255)/256, 256, 0, stream>>>(ei, deg_i);
    k_scan<<<1, 1024, 0, stream>>>(deg_i, offs, avglog);
    k_fill<<<(E_ + 255)/256, 256, 0, stream>>>(ei, eattr, offs, cursor, csr);
    k_amp<<<(N_ + 255)/256, 256, 0, stream>>>(deg_i, avglog, ampv, iampv);
    k_eemb<<<(4*4*FIN_ + 255)/256, 256, 0, stream>>>(edge_emb, We, be, eembw);
    k_tbl<<<(4*4*TF_ + 255)/256, 256, 0, stream>>>(eembw, Wpre, bpre, tbl);
    k_wcomb<<<(4*T_*TF_*YC_ + 255)/256, 256, 0, stream>>>(Wpost, Wcomb);

    int nrb = (N_ + 127)/128;  // 79
    for (int l = 0; l < 4; l++){
        hipMemsetAsync(bnsum, 0, 2*FIN_*4, stream);
        k_A<<<dim3(nrb, 10), 128, 0, stream>>>(h80, Wpre + (size_t)l*T_*225*FIN_, AB);
        k_agg<<<N_, 128, 0, stream>>>(AB, offs, csr, tbl + (size_t)l*4*TF_, aggb);
        k_post2<<<dim3(nrb, T_), 128, 0, stream>>>(h80, aggb, Wcomb + (size_t)l*T_*TF_*YC_, Yb);
        k_Y<<<(N_ + 31)/32, 256, 0, stream>>>(Yb, ampv, iampv, bpost + l*T_*FOUT_,
                                              Wlin + (size_t)l*FIN_*FIN_, blin + l*FIN_,
                                              olin, bnsum, bnsq);
        k_bn<<<(N_*H80 + 255)/256, 256, 0, stream>>>(olin, bnsum, bnsq,
                                                     bn_gamma + l*FIN_, bn_beta + l*FIN_, uafp, h80);
    }

    k_pool<<<(N_*FIN_ + 255)/256, 256, 0, stream>>>(h80, batch, pooled);
    k_mlp<<<G_, 64, 0, stream>>>(pooled, mW1, mb1, mW2, mb2, mW3, mb3, uafp, outp);
}